// Round 1
// baseline (2119.390 us; speedup 1.0000x reference)
//
#include <hip/hip_runtime.h>
#include <math.h>

#define B_ 8
#define N_ 4096
#define C_ 768
#define H_ 3072
#define M_ (B_*N_)
#define NSPLIT 16

typedef unsigned short u16;
typedef unsigned int u32;
typedef __attribute__((ext_vector_type(8))) __bf16 bf16x8;
typedef __attribute__((ext_vector_type(4))) float f32x4;

__device__ __forceinline__ u16 f2bf(float f){
  u32 u = __float_as_uint(f);
  u32 r = (u + 0x7FFFu + ((u >> 16) & 1u)) >> 16;
  return (u16)r;
}
__device__ __forceinline__ float bf2f(u16 h){
  return __uint_as_float(((u32)h) << 16);
}
__device__ __forceinline__ void gload_lds16(const void* g, void* l){
  __builtin_amdgcn_global_load_lds((const __attribute__((address_space(1))) void*)g,
                                   (__attribute__((address_space(3))) void*)l, 16, 0, 0);
}

// ---------------- GEMM: C[M,N] = A[M,K](bf16) * BT[N,K](bf16)^T ----------------
// 128x128 block tile, 4 waves (2x2), each wave 64x64 via 4x4 mfma_f32_16x16x32_bf16.
// EPI: 0 = write bf16
//      1 = out_f32 = resid + acc + rowv[batch(row)]   (xo/yo projection)
//      2 = out_bf16 = gelu(acc + bias)                (MLP hidden)
//      3 = out_f32 += acc + bias                      (MLP second GEMM)
template<int EPI>
__global__ __launch_bounds__(256) void gemm_bf16(
    const u16* __restrict__ A, const u16* __restrict__ BT,
    int K, int N,
    void* __restrict__ outp,
    const float* __restrict__ resid,
    const float* __restrict__ rowv,
    const float* __restrict__ bias)
{
  __shared__ u16 ldsA[128*32];
  __shared__ u16 ldsB[128*32];
  const int tid = threadIdx.x;
  const int wid = tid >> 6, lane = tid & 63;
  const int bm = blockIdx.x * 128, bn = blockIdx.y * 128;
  const int wr = wid >> 1, wc = wid & 1;

  f32x4 acc[4][4];
#pragma unroll
  for (int i=0;i<4;i++)
#pragma unroll
    for (int j=0;j<4;j++) acc[i][j] = (f32x4){0.f,0.f,0.f,0.f};

  const int idx0 = tid, idx1 = tid + 256;
  const u16* agp0 = A  + (size_t)(bm + (idx0>>2))*K + (idx0&3)*8;
  const u16* agp1 = A  + (size_t)(bm + (idx1>>2))*K + (idx1&3)*8;
  const u16* bgp0 = BT + (size_t)(bn + (idx0>>2))*K + (idx0&3)*8;
  const u16* bgp1 = BT + (size_t)(bn + (idx1>>2))*K + (idx1&3)*8;
  u16* la0 = ldsA + (wid*64)*8;
  u16* la1 = ldsA + (256 + wid*64)*8;
  u16* lb0 = ldsB + (wid*64)*8;
  u16* lb1 = ldsB + (256 + wid*64)*8;

  const int aoff = (wr*64 + (lane&15))*32 + (lane>>4)*8;
  const int boff = (wc*64 + (lane&15))*32 + (lane>>4)*8;

  const int nk = K >> 5;
  for (int kk=0; kk<nk; kk++){
    __syncthreads();              // all waves done reading previous tile
    gload_lds16(agp0, la0);
    gload_lds16(agp1, la1);
    gload_lds16(bgp0, lb0);
    gload_lds16(bgp1, lb1);
    agp0 += 32; agp1 += 32; bgp0 += 32; bgp1 += 32;
    __syncthreads();              // staging complete (drains vmcnt)
    bf16x8 av[4], bv[4];
#pragma unroll
    for (int i=0;i<4;i++){
      av[i] = *reinterpret_cast<const bf16x8*>(&ldsA[aoff + i*16*32]);
      bv[i] = *reinterpret_cast<const bf16x8*>(&ldsB[boff + i*16*32]);
    }
#pragma unroll
    for (int i=0;i<4;i++)
#pragma unroll
      for (int j=0;j<4;j++)
        acc[i][j] = __builtin_amdgcn_mfma_f32_16x16x32_bf16(av[i], bv[j], acc[i][j], 0, 0, 0);
  }

  // C/D layout (verified m89): col = lane&15, row = (lane>>4)*4 + r
  const int col0 = bn + wc*64 + (lane & 15);
  const int row0 = bm + wr*64 + ((lane >> 4) << 2);
#pragma unroll
  for (int i=0;i<4;i++){
#pragma unroll
    for (int j=0;j<4;j++){
#pragma unroll
      for (int r=0;r<4;r++){
        const int row = row0 + i*16 + r;
        const int cj  = col0 + j*16;
        const size_t o = (size_t)row*N + cj;
        const float va = acc[i][j][r];
        if constexpr (EPI == 0){
          ((u16*)outp)[o] = f2bf(va);
        } else if constexpr (EPI == 1){
          ((float*)outp)[o] = resid[o] + va + rowv[(row >> 12)*N + cj];
        } else if constexpr (EPI == 2){
          const float z = va + bias[cj];
          ((u16*)outp)[o] = f2bf(0.5f*z*(1.0f + erff(z*0.70710678f)));
        } else {
          float* po = (float*)outp + o;
          *po += va + bias[cj];
        }
      }
    }
  }
}

// ---------------- LayerNorm over last dim (768), writes bf16 ----------------
__global__ __launch_bounds__(256) void ln_fwd(const float* __restrict__ in,
    const float* __restrict__ gam, const float* __restrict__ bet,
    u16* __restrict__ out)
{
  const int row = blockIdx.x;
  const int tid = threadIdx.x;
  const float* p = in + (size_t)row * C_;
  float v0 = p[tid], v1 = p[tid+256], v2 = p[tid+512];
  float s = v0+v1+v2, sq = v0*v0+v1*v1+v2*v2;
  __shared__ float sm[8];
#pragma unroll
  for (int o=32;o>0;o>>=1){ s += __shfl_down(s,o); sq += __shfl_down(sq,o); }
  if ((tid&63)==0){ sm[tid>>6]=s; sm[4+(tid>>6)]=sq; }
  __syncthreads();
  s  = sm[0]+sm[1]+sm[2]+sm[3];
  sq = sm[4]+sm[5]+sm[6]+sm[7];
  const float mu = s * (1.f/C_);
  const float rs = rsqrtf(sq*(1.f/C_) - mu*mu + 1e-5f);
  u16* op = out + (size_t)row * C_;
  op[tid]     = f2bf((v0-mu)*rs*gam[tid]     + bet[tid]);
  op[tid+256] = f2bf((v1-mu)*rs*gam[tid+256] + bet[tid+256]);
  op[tid+512] = f2bf((v2-mu)*rs*gam[tid+512] + bet[tid+512]);
}

// ---------------- f32 -> bf16 convert (vectorized) ----------------
__global__ __launch_bounds__(256) void cvt_bf16(const float* __restrict__ in,
                                                u16* __restrict__ out, int n4)
{
  int i = blockIdx.x*256 + threadIdx.x;
  if (i < n4){
    float4 v = reinterpret_cast<const float4*>(in)[i];
    u16* o = out + (size_t)i*4;
    o[0]=f2bf(v.x); o[1]=f2bf(v.y); o[2]=f2bf(v.z); o[3]=f2bf(v.w);
  }
}

// ---------------- transpose + convert: in[R,Cc] f32 -> out[Cc,R] bf16 ----------------
__global__ __launch_bounds__(256) void transpose_cvt(const float* __restrict__ in,
    u16* __restrict__ out, int R, int Cc)
{
  __shared__ float tile[32][33];
  const int c0 = blockIdx.x*32, r0 = blockIdx.y*32;
  const int tx = threadIdx.x & 31, ty = threadIdx.x >> 5;
#pragma unroll
  for (int i=0;i<32;i+=8)
    tile[ty+i][tx] = in[(size_t)(r0+ty+i)*Cc + c0+tx];
  __syncthreads();
#pragma unroll
  for (int i=0;i<32;i+=8)
    out[(size_t)(c0+ty+i)*R + r0+tx] = f2bf(tile[tx][ty+i]);
}

// ---------------- mask sum per batch ----------------
__global__ __launch_bounds__(256) void msum_kernel(const float* __restrict__ mask,
                                                   float* __restrict__ msum)
{
  __shared__ float sm[4];
  const int b = blockIdx.x;
  float s = 0.f;
  for (int i=threadIdx.x;i<N_;i+=256) s += mask[(size_t)b*N_+i];
#pragma unroll
  for (int o=32;o>0;o>>=1) s += __shfl_down(s,o);
  if ((threadIdx.x&63)==0) sm[threadIdx.x>>6]=s;
  __syncthreads();
  if (threadIdx.x==0) msum[b] = sm[0]+sm[1]+sm[2]+sm[3];
}

// ---------------- masked pooling partials over n-chunks ----------------
__global__ __launch_bounds__(256) void pool_partial(const u16* __restrict__ q,
    const float* __restrict__ mask, float* __restrict__ pm, float* __restrict__ pa)
{
  const int c = blockIdx.x*256 + threadIdx.x;
  const int b = blockIdx.y, z = blockIdx.z;
  const int n0 = z*(N_/NSPLIT);
  const u16* qp = q + ((size_t)b*N_ + n0)*C_ + c;
  const float* mp = mask + (size_t)b*N_ + n0;
  float am=0.f, aa=0.f;
  for (int n=0;n<N_/NSPLIT;n++){
    float v = bf2f(qp[(size_t)n*C_]);
    float m = mp[n];
    am += v*m; aa += v;
  }
  const size_t o = ((size_t)z*B_ + b)*C_ + c;
  pm[o]=am; pa[o]=aa;
}

__global__ __launch_bounds__(256) void pool_final(const float* __restrict__ pm,
    const float* __restrict__ pa, const float* __restrict__ msum,
    float* __restrict__ fg, float* __restrict__ bg)
{
  const int c = blockIdx.x*256 + threadIdx.x;
  const int b = blockIdx.y;
  float s_m=0.f, s_a=0.f;
  for (int z=0;z<NSPLIT;z++){ size_t o=((size_t)z*B_+b)*C_+c; s_m+=pm[o]; s_a+=pa[o]; }
  const float ms = msum[b];
  fg[b*C_+c] = s_m/(ms + 5e-4f);
  bg[b*C_+c] = (s_a - s_m)/((float)N_ - ms + 5e-4f);
}

__global__ __launch_bounds__(256) void norm_kernel(const float* __restrict__ fg,
    const float* __restrict__ bg, float* __restrict__ fgn, float* __restrict__ bgn)
{
  __shared__ float sm[8];
  const int b = blockIdx.x;
  float f=0.f, g=0.f;
  for (int i=threadIdx.x;i<C_;i+=256){
    float a=fg[b*C_+i]; f+=a*a;
    float c=bg[b*C_+i]; g+=c*c;
  }
#pragma unroll
  for (int o=32;o>0;o>>=1){ f+=__shfl_down(f,o); g+=__shfl_down(g,o); }
  if ((threadIdx.x&63)==0){ sm[threadIdx.x>>6]=f; sm[4+(threadIdx.x>>6)]=g; }
  __syncthreads();
  if (threadIdx.x==0){
    fgn[b]=sqrtf(sm[0]+sm[1]+sm[2]+sm[3]);
    bgn[b]=sqrtf(sm[4]+sm[5]+sm[6]+sm[7]);
  }
}

// ---------------- cosine scores per token ----------------
__global__ __launch_bounds__(256) void score_kernel(const u16* __restrict__ k,
    const float* __restrict__ fg, const float* __restrict__ bg,
    const float* __restrict__ fgn, const float* __restrict__ bgn,
    float* __restrict__ fg_s, float* __restrict__ bg_s)
{
  __shared__ float sm[12];
  const int t = blockIdx.x;
  const int b = t >> 12;
  const u16* kp = k + (size_t)t*C_;
  float df=0.f, db=0.f, kk=0.f;
  for (int i=threadIdx.x;i<C_;i+=256){
    float kv = bf2f(kp[i]);
    df += kv*fg[b*C_+i]; db += kv*bg[b*C_+i]; kk += kv*kv;
  }
#pragma unroll
  for (int o=32;o>0;o>>=1){ df+=__shfl_down(df,o); db+=__shfl_down(db,o); kk+=__shfl_down(kk,o); }
  const int wid = threadIdx.x>>6;
  if ((threadIdx.x&63)==0){ sm[wid]=df; sm[4+wid]=db; sm[8+wid]=kk; }
  __syncthreads();
  if (threadIdx.x==0){
    df=sm[0]+sm[1]+sm[2]+sm[3]; db=sm[4]+sm[5]+sm[6]+sm[7]; kk=sm[8]+sm[9]+sm[10]+sm[11];
    const float kn = sqrtf(kk);
    fg_s[t] = df/(kn*fgn[b]+1e-7f);
    bg_s[t] = db/(kn*bgn[b]+1e-7f);
  }
}

__global__ __launch_bounds__(256) void minmax_kernel(const float* __restrict__ fg_s,
    const float* __restrict__ bg_s, float* __restrict__ mm)
{
  __shared__ float sm[16];
  const int b = blockIdx.x;
  float mnf=1e30f, mxf=-1e30f, mnb=1e30f, mxb=-1e30f;
  for (int i=threadIdx.x;i<N_;i+=256){
    float a = fg_s[(size_t)b*N_+i]; mnf=fminf(mnf,a); mxf=fmaxf(mxf,a);
    float c = bg_s[(size_t)b*N_+i]; mnb=fminf(mnb,c); mxb=fmaxf(mxb,c);
  }
#pragma unroll
  for (int o=32;o>0;o>>=1){
    mnf=fminf(mnf,__shfl_down(mnf,o)); mxf=fmaxf(mxf,__shfl_down(mxf,o));
    mnb=fminf(mnb,__shfl_down(mnb,o)); mxb=fmaxf(mxb,__shfl_down(mxb,o));
  }
  const int wid = threadIdx.x>>6;
  if ((threadIdx.x&63)==0){ sm[wid]=mnf; sm[4+wid]=mxf; sm[8+wid]=mnb; sm[12+wid]=mxb; }
  __syncthreads();
  if (threadIdx.x==0){
    mm[b*4+0]=fminf(fminf(sm[0],sm[1]),fminf(sm[2],sm[3]));
    mm[b*4+1]=fmaxf(fmaxf(sm[4],sm[5]),fmaxf(sm[6],sm[7]));
    mm[b*4+2]=fminf(fminf(sm[8],sm[9]),fminf(sm[10],sm[11]));
    mm[b*4+3]=fmaxf(fmaxf(sm[12],sm[13]),fmaxf(sm[14],sm[15]));
  }
}

// scores -> pseudo_mask out, exp weights, per-block exp partial sums
__global__ __launch_bounds__(256) void scorefin_kernel(const float* __restrict__ fg_s,
    const float* __restrict__ bg_s, const float* __restrict__ mm,
    float* __restrict__ pseudo, float* __restrict__ escr, float* __restrict__ epart)
{
  __shared__ float sm[4];
  const int b = blockIdx.y, z = blockIdx.x;
  const int t = z*256 + threadIdx.x;
  const size_t o = (size_t)b*N_ + t;
  const float mnf=mm[b*4+0], mxf=mm[b*4+1], mnb=mm[b*4+2], mxb=mm[b*4+3];
  const float s = (fg_s[o]-mnf)/(mxf-mnf+1e-7f) - (bg_s[o]-mnb)/(mxb-mnb+1e-7f);
  pseudo[o] = s;
  // softmax(where(s<0, s-100, s)); z<=~1 so exp() never overflows, skip max-sub
  const float e = expf(s < 0.f ? s - 100.f : s);
  escr[o] = e;
  float ps = e;
#pragma unroll
  for (int off=32;off>0;off>>=1) ps += __shfl_down(ps,off);
  if ((threadIdx.x&63)==0) sm[threadIdx.x>>6]=ps;
  __syncthreads();
  if (threadIdx.x==0) epart[b*16+z] = sm[0]+sm[1]+sm[2]+sm[3];
}

__global__ void denom_kernel(const float* __restrict__ epart, float* __restrict__ denom){
  const int b = threadIdx.x;
  if (b < B_){ float s=0.f; for (int z=0;z<16;z++) s+=epart[b*16+z]; denom[b]=s; }
}

__global__ __launch_bounds__(256) void vsum_partial(const u16* __restrict__ v,
    const float* __restrict__ e, float* __restrict__ pv)
{
  const int c = blockIdx.x*256 + threadIdx.x;
  const int b = blockIdx.y, z = blockIdx.z;
  const int n0 = z*(N_/NSPLIT);
  const u16* vp = v + ((size_t)b*N_ + n0)*C_ + c;
  const float* ep = e + (size_t)b*N_ + n0;
  float acc=0.f;
  for (int n=0;n<N_/NSPLIT;n++) acc += bf2f(vp[(size_t)n*C_])*ep[n];
  pv[((size_t)z*B_+b)*C_+c] = acc;
}

__global__ __launch_bounds__(256) void vsum_final(const float* __restrict__ pv,
    const float* __restrict__ denom, float* __restrict__ qp)
{
  const int c = blockIdx.x*256 + threadIdx.x;
  const int b = blockIdx.y;
  float s=0.f;
  for (int z=0;z<NSPLIT;z++) s += pv[((size_t)z*B_+b)*C_+c];
  qp[b*C_+c] = s/denom[b];
}

__global__ __launch_bounds__(256) void pro_kernel(const float* __restrict__ qp,
    const float* __restrict__ fg, const float* __restrict__ fgn, float* __restrict__ pro)
{
  __shared__ float sm[8];
  __shared__ float simsh;
  const int b = blockIdx.x;
  float d=0.f, qq=0.f;
  for (int i=threadIdx.x;i<C_;i+=256){ float a=qp[b*C_+i]; d+=a*fg[b*C_+i]; qq+=a*a; }
#pragma unroll
  for (int o=32;o>0;o>>=1){ d+=__shfl_down(d,o); qq+=__shfl_down(qq,o); }
  if ((threadIdx.x&63)==0){ sm[threadIdx.x>>6]=d; sm[4+(threadIdx.x>>6)]=qq; }
  __syncthreads();
  if (threadIdx.x==0){
    d=sm[0]+sm[1]+sm[2]+sm[3]; qq=sm[4]+sm[5]+sm[6]+sm[7];
    simsh = (d/(sqrtf(qq)*fgn[b]+1e-7f)+1.f)*0.5f;
  }
  __syncthreads();
  const float sim = simsh;
  for (int i=threadIdx.x;i<C_;i+=256)
    pro[b*C_+i] = sim*fg[b*C_+i] + (1.f-sim)*qp[b*C_+i];
}

// rowv[b][j] = sum_c pro[b][c] * Wp[(C_+c)*C_ + j]   (bottom half of Wpx/Wpy, f32)
__global__ __launch_bounds__(256) void rowvec_kernel(const float* __restrict__ pro,
    const float* __restrict__ Wp, float* __restrict__ row)
{
  const int j = blockIdx.x*256 + threadIdx.x;
  const int b = blockIdx.y;
  const float* w = Wp + (size_t)C_*C_ + j;
  const float* p = pro + b*C_;
  float acc=0.f;
#pragma unroll 4
  for (int c=0;c<C_;c++) acc += p[c]*w[(size_t)c*C_];
  row[b*C_+j] = acc;
}

// ---------------- launcher ----------------
extern "C" void kernel_launch(void* const* d_in, const int* in_sizes, int n_in,
                              void* d_out, int out_size, void* d_ws, size_t ws_size,
                              hipStream_t stream)
{
  const float* x     = (const float*)d_in[0];
  const float* y     = (const float*)d_in[1];
  const float* mask  = (const float*)d_in[2];
  const float* ln1_g = (const float*)d_in[5];
  const float* ln1_b = (const float*)d_in[6];
  const float* Wq    = (const float*)d_in[7];
  const float* Wk    = (const float*)d_in[8];
  const float* Wv    = (const float*)d_in[9];
  const float* Wpx   = (const float*)d_in[10];
  const float* Wpy   = (const float*)d_in[11];
  const float* ln2_g = (const float*)d_in[12];
  const float* ln2_b = (const float*)d_in[13];
  const float* fx1_w = (const float*)d_in[14];
  const float* fx1_b = (const float*)d_in[15];
  const float* fx2_w = (const float*)d_in[16];
  const float* fx2_b = (const float*)d_in[17];
  const float* fy1_w = (const float*)d_in[18];
  const float* fy1_b = (const float*)d_in[19];
  const float* fy2_w = (const float*)d_in[20];
  const float* fy2_b = (const float*)d_in[21];

  float* out    = (float*)d_out;
  float* out_xo = out;
  float* out_yo = out + (size_t)M_*C_;
  float* out_ps = out + 2*(size_t)M_*C_;

  char* ws = (char*)d_ws;
  const size_t ACT = (size_t)M_*C_;        // 25165824 elems
  u16* R0  = (u16*)ws;                     // 201.3 MB region
  u16* xnb = R0;                           // xn bf16 (later: x bf16)
  u16* ynb = R0 + ACT;                     // yn bf16 (later: y bf16)
  u16* kb  = R0 + 2*ACT;                   // k bf16
  u16* vb  = R0 + 3*ACT;                   // v bf16
  u16* hid = R0;                           // MLP hidden bf16 [M,H] aliases all of R
  u16* qb  = (u16*)(ws + 4*ACT*2);         // q bf16 (later: ln2 out bf16)
  u16* wp  = (u16*)(ws + 5*ACT*2);         // bf16 weights
  u16* WqT  = wp;
  u16* WkT  = wp + 1*589824;
  u16* WvT  = wp + 2*589824;
  u16* WpxT = wp + 3*589824;
  u16* WpyT = wp + 4*589824;
  u16* fx1T = wp + 5*589824;
  u16* fx2T = fx1T + 2359296;
  u16* fy1T = fx2T + 2359296;
  u16* fy2T = fy1T + 2359296;
  float* st   = (float*)(ws + 5*ACT*2 + 24772608);
  float* msum = st;             // 8
  float* fgn  = st + 8;         // 8
  float* bgn  = st + 16;        // 8
  float* denom= st + 24;        // 8
  float* mm   = st + 32;        // 32
  float* fg   = st + 64;        // 6144
  float* bg   = st + 6208;      // 6144
  float* qp   = st + 12352;     // 6144
  float* pro  = st + 18496;     // 6144
  float* rowx = st + 24640;     // 6144
  float* rowy = st + 30784;     // 6144
  float* epart= st + 36928;     // 128
  float* fg_s = st + 37056;     // 32768
  float* bg_s = st + 69824;     // 32768
  float* escr = st + 102592;    // 32768
  float* pm   = st + 135360;    // 98304
  float* pa   = st + 233664;    // 98304
  float* pv   = st + 331968;    // 98304

  dim3 tb(256);

  // --- weights -> bf16, transposed to [N,K] ---
  transpose_cvt<<<dim3(24,24),tb,0,stream>>>(Wq,  WqT,  C_, C_);
  transpose_cvt<<<dim3(24,24),tb,0,stream>>>(Wk,  WkT,  C_, C_);
  transpose_cvt<<<dim3(24,24),tb,0,stream>>>(Wv,  WvT,  C_, C_);
  transpose_cvt<<<dim3(24,24),tb,0,stream>>>(Wpx, WpxT, C_, C_);   // top half of (1536,768)
  transpose_cvt<<<dim3(24,24),tb,0,stream>>>(Wpy, WpyT, C_, C_);
  transpose_cvt<<<dim3(96,24),tb,0,stream>>>(fx1_w, fx1T, C_, H_); // (768,3072) -> (3072,768)
  transpose_cvt<<<dim3(24,96),tb,0,stream>>>(fx2_w, fx2T, H_, C_); // (3072,768) -> (768,3072)
  transpose_cvt<<<dim3(96,24),tb,0,stream>>>(fy1_w, fy1T, C_, H_);
  transpose_cvt<<<dim3(24,96),tb,0,stream>>>(fy2_w, fy2T, H_, C_);

  // --- LN1 ---
  ln_fwd<<<M_,tb,0,stream>>>(x, ln1_g, ln1_b, xnb);
  ln_fwd<<<M_,tb,0,stream>>>(y, ln1_g, ln1_b, ynb);

  // --- q,k,v GEMMs ---
  gemm_bf16<0><<<dim3(M_/128, C_/128),tb,0,stream>>>(ynb, WqT, C_, C_, qb, nullptr,nullptr,nullptr);
  gemm_bf16<0><<<dim3(M_/128, C_/128),tb,0,stream>>>(xnb, WkT, C_, C_, kb, nullptr,nullptr,nullptr);
  gemm_bf16<0><<<dim3(M_/128, C_/128),tb,0,stream>>>(xnb, WvT, C_, C_, vb, nullptr,nullptr,nullptr);

  // --- pooled prototypes + scores ---
  msum_kernel<<<B_,tb,0,stream>>>(mask, msum);
  pool_partial<<<dim3(3,B_,NSPLIT),tb,0,stream>>>(qb, mask, pm, pa);
  pool_final<<<dim3(3,B_),tb,0,stream>>>(pm, pa, msum, fg, bg);
  norm_kernel<<<B_,tb,0,stream>>>(fg, bg, fgn, bgn);
  score_kernel<<<M_,tb,0,stream>>>(kb, fg, bg, fgn, bgn, fg_s, bg_s);
  minmax_kernel<<<B_,tb,0,stream>>>(fg_s, bg_s, mm);
  scorefin_kernel<<<dim3(16,B_),tb,0,stream>>>(fg_s, bg_s, mm, out_ps, escr, epart);
  denom_kernel<<<1,64,0,stream>>>(epart, denom);
  vsum_partial<<<dim3(3,B_,NSPLIT),tb,0,stream>>>(vb, escr, pv);
  vsum_final<<<dim3(3,B_),tb,0,stream>>>(pv, denom, qp);
  pro_kernel<<<B_,tb,0,stream>>>(qp, fg, fgn, pro);
  rowvec_kernel<<<dim3(3,B_),tb,0,stream>>>(pro, Wpx, rowx);
  rowvec_kernel<<<dim3(3,B_),tb,0,stream>>>(pro, Wpy, rowy);

  // --- x,y -> bf16 (reuse xn/yn slots; xn/yn dead after qkv GEMMs) ---
  cvt_bf16<<<(ACT/4+255)/256,tb,0,stream>>>(x, xnb, (int)(ACT/4));
  cvt_bf16<<<(ACT/4+255)/256,tb,0,stream>>>(y, ynb, (int)(ACT/4));

  // --- projection GEMMs: out = resid + act@WpA + pro@WpB ---
  gemm_bf16<1><<<dim3(M_/128, C_/128),tb,0,stream>>>(xnb, WpxT, C_, C_, out_xo, x, rowx, nullptr);
  gemm_bf16<1><<<dim3(M_/128, C_/128),tb,0,stream>>>(ynb, WpyT, C_, C_, out_yo, y, rowy, nullptr);

  // --- x MLP ---
  ln_fwd<<<M_,tb,0,stream>>>(out_xo, ln2_g, ln2_b, qb);
  gemm_bf16<2><<<dim3(M_/128, H_/128),tb,0,stream>>>(qb, fx1T, C_, H_, hid, nullptr,nullptr, fx1_b);
  gemm_bf16<3><<<dim3(M_/128, C_/128),tb,0,stream>>>(hid, fx2T, H_, C_, out_xo, nullptr,nullptr, fx2_b);

  // --- y MLP ---
  ln_fwd<<<M_,tb,0,stream>>>(out_yo, ln2_g, ln2_b, qb);
  gemm_bf16<2><<<dim3(M_/128, H_/128),tb,0,stream>>>(qb, fy1T, C_, H_, hid, nullptr,nullptr, fy1_b);
  gemm_bf16<3><<<dim3(M_/128, C_/128),tb,0,stream>>>(hid, fy2T, H_, C_, out_yo, nullptr,nullptr, fy2_b);
}

// Round 2
// 1802.710 us; speedup vs baseline: 1.1757x; 1.1757x over previous
//
#include <hip/hip_runtime.h>
#include <math.h>

#define B_ 8
#define N_ 4096
#define C_ 768
#define H_ 3072
#define M_ (B_*N_)
#define NSPLIT 16

typedef unsigned short u16;
typedef unsigned int u32;
typedef __attribute__((ext_vector_type(8))) __bf16 bf16x8;
typedef __attribute__((ext_vector_type(4))) float f32x4;
typedef __attribute__((ext_vector_type(4))) unsigned short u16x4;

__device__ __forceinline__ u16 f2bf(float f){
  u32 u = __float_as_uint(f);
  u32 r = (u + 0x7FFFu + ((u >> 16) & 1u)) >> 16;
  return (u16)r;
}
__device__ __forceinline__ float bf2f(u16 h){
  return __uint_as_float(((u32)h) << 16);
}
__device__ __forceinline__ void gload_lds16(const void* g, void* l){
  __builtin_amdgcn_global_load_lds((const __attribute__((address_space(1))) void*)g,
                                   (__attribute__((address_space(3))) void*)l, 16, 0, 0);
}

// ---------------- GEMM: C[M,N] = A[M,K](bf16) * BT[N,K](bf16)^T ----------------
// 128x128 tile, 4 waves (2x2), 4x4 mfma_f32_16x16x32_bf16 per wave.
// 2-phase pipeline: double-buffered LDS, STAGE(next) issued before compute(cur),
// single __syncthreads per K-iter (drains vmcnt for the stage + protects reuse).
// Grid: 1D, XCD-swizzled (nwg%8==0 guaranteed) + GM=8 row-panel grouping for L2.
// EPI: 0 = write bf16
//      1 = out_f32 = resid + acc + rowv[batch(row)]   (xo/yo projection)
//      2 = out_bf16 = gelu(acc + bias)                (MLP hidden)
//      3 = out_f32 += acc + bias                      (MLP second GEMM)
template<int EPI>
__global__ __launch_bounds__(256) void gemm_bf16(
    const u16* __restrict__ A, const u16* __restrict__ BT,
    int K, int N, int NBN,
    void* __restrict__ outp,
    const float* __restrict__ resid,
    const float* __restrict__ rowv,
    const float* __restrict__ bias)
{
  __shared__ u16 lds[2][8192];   // per buf: A[128][32] then B[128][32]  (16 KiB), x2 dbuf = 32 KiB
  const int tid = threadIdx.x;
  const int wid = tid >> 6, lane = tid & 63;

  // --- block swizzle: XCD chunk + GM=8 row grouping ---
  const int nwg = gridDim.x;
  int wg = blockIdx.x;
  wg = (wg & 7) * (nwg >> 3) + (wg >> 3);      // bijective (nwg%8==0)
  const int GMN = 8 * NBN;
  const int g = wg / GMN, r = wg % GMN;
  const int bm = (g*8 + (r & 7)) * 128;
  const int bn = (r >> 3) * 128;

  const int wr = wid >> 1, wc = wid & 1;

  f32x4 acc[4][4];
#pragma unroll
  for (int i=0;i<4;i++)
#pragma unroll
    for (int j=0;j<4;j++) acc[i][j] = (f32x4){0.f,0.f,0.f,0.f};

  const int idx0 = tid, idx1 = tid + 256;
  const u16* agp0 = A  + (size_t)(bm + (idx0>>2))*K + (idx0&3)*8;
  const u16* agp1 = A  + (size_t)(bm + (idx1>>2))*K + (idx1&3)*8;
  const u16* bgp0 = BT + (size_t)(bn + (idx0>>2))*K + (idx0&3)*8;
  const u16* bgp1 = BT + (size_t)(bn + (idx1>>2))*K + (idx1&3)*8;

  auto STAGE = [&](int c){
    u16* base = lds[c];
    gload_lds16(agp0, base + wid*512);           // A rows 0..63   (this wave's 64 lanes)
    gload_lds16(agp1, base + 2048 + wid*512);    // A rows 64..127
    gload_lds16(bgp0, base + 4096 + wid*512);    // B rows 0..63
    gload_lds16(bgp1, base + 6144 + wid*512);    // B rows 64..127
    agp0 += 32; agp1 += 32; bgp0 += 32; bgp1 += 32;
  };

  const int aoff = (wr*64 + (lane&15))*32 + (lane>>4)*8;
  const int boff = 4096 + (wc*64 + (lane&15))*32 + (lane>>4)*8;

  const int nk = K >> 5;
  STAGE(0);
  __syncthreads();               // drains vmcnt(0): buf0 ready
  int cur = 0;
  for (int kk=0; kk<nk; kk++){
    if (kk+1 < nk) STAGE(cur^1); // issue next-tile loads BEFORE compute (overlap)
    bf16x8 av[4], bv[4];
    const u16* pa = &lds[cur][aoff];
    const u16* pb = &lds[cur][boff];
#pragma unroll
    for (int i=0;i<4;i++){
      av[i] = *reinterpret_cast<const bf16x8*>(pa + i*512);
      bv[i] = *reinterpret_cast<const bf16x8*>(pb + i*512);
    }
#pragma unroll
    for (int i=0;i<4;i++)
#pragma unroll
      for (int j=0;j<4;j++)
        acc[i][j] = __builtin_amdgcn_mfma_f32_16x16x32_bf16(av[i], bv[j], acc[i][j], 0, 0, 0);
    __syncthreads();             // all reads of buf[cur] done + stage into buf[cur^1] landed
    cur ^= 1;
  }

  // C/D layout (verified m89): col = lane&15, row = (lane>>4)*4 + r
  const int col0 = bn + wc*64 + (lane & 15);
  const int row0 = bm + wr*64 + ((lane >> 4) << 2);
#pragma unroll
  for (int i=0;i<4;i++){
#pragma unroll
    for (int j=0;j<4;j++){
#pragma unroll
      for (int r2=0;r2<4;r2++){
        const int row = row0 + i*16 + r2;
        const int cj  = col0 + j*16;
        const size_t o = (size_t)row*N + cj;
        const float va = acc[i][j][r2];
        if constexpr (EPI == 0){
          ((u16*)outp)[o] = f2bf(va);
        } else if constexpr (EPI == 1){
          ((float*)outp)[o] = resid[o] + va + rowv[(row >> 12)*N + cj];
        } else if constexpr (EPI == 2){
          const float z = va + bias[cj];
          ((u16*)outp)[o] = f2bf(0.5f*z*(1.0f + erff(z*0.70710678f)));
        } else {
          float* po = (float*)outp + o;
          *po += va + bias[cj];
        }
      }
    }
  }
}

// ---------------- LayerNorm over last dim (768): wave-per-row, float4 ----------------
__global__ __launch_bounds__(256) void ln_fwd(const float* __restrict__ in,
    const float* __restrict__ gam, const float* __restrict__ bet,
    u16* __restrict__ out)
{
  const int row  = blockIdx.x*4 + (threadIdx.x >> 6);
  const int lane = threadIdx.x & 63;
  const float* p = in + (size_t)row * C_;
  float4 v0 = *reinterpret_cast<const float4*>(p + lane*4);
  float4 v1 = *reinterpret_cast<const float4*>(p + lane*4 + 256);
  float4 v2 = *reinterpret_cast<const float4*>(p + lane*4 + 512);
  float s  = v0.x+v0.y+v0.z+v0.w + v1.x+v1.y+v1.z+v1.w + v2.x+v2.y+v2.z+v2.w;
  float sq = v0.x*v0.x+v0.y*v0.y+v0.z*v0.z+v0.w*v0.w
           + v1.x*v1.x+v1.y*v1.y+v1.z*v1.z+v1.w*v1.w
           + v2.x*v2.x+v2.y*v2.y+v2.z*v2.z+v2.w*v2.w;
#pragma unroll
  for (int o=32;o>0;o>>=1){ s += __shfl_xor(s,o); sq += __shfl_xor(sq,o); }
  const float mu = s * (1.f/C_);
  const float rs = rsqrtf(sq*(1.f/C_) - mu*mu + 1e-5f);
  float4 g0 = *reinterpret_cast<const float4*>(gam + lane*4);
  float4 g1 = *reinterpret_cast<const float4*>(gam + lane*4 + 256);
  float4 g2 = *reinterpret_cast<const float4*>(gam + lane*4 + 512);
  float4 b0 = *reinterpret_cast<const float4*>(bet + lane*4);
  float4 b1 = *reinterpret_cast<const float4*>(bet + lane*4 + 256);
  float4 b2 = *reinterpret_cast<const float4*>(bet + lane*4 + 512);
  u16* op = out + (size_t)row * C_;
  u16x4 o0, o1, o2;
  o0[0]=f2bf((v0.x-mu)*rs*g0.x+b0.x); o0[1]=f2bf((v0.y-mu)*rs*g0.y+b0.y);
  o0[2]=f2bf((v0.z-mu)*rs*g0.z+b0.z); o0[3]=f2bf((v0.w-mu)*rs*g0.w+b0.w);
  o1[0]=f2bf((v1.x-mu)*rs*g1.x+b1.x); o1[1]=f2bf((v1.y-mu)*rs*g1.y+b1.y);
  o1[2]=f2bf((v1.z-mu)*rs*g1.z+b1.z); o1[3]=f2bf((v1.w-mu)*rs*g1.w+b1.w);
  o2[0]=f2bf((v2.x-mu)*rs*g2.x+b2.x); o2[1]=f2bf((v2.y-mu)*rs*g2.y+b2.y);
  o2[2]=f2bf((v2.z-mu)*rs*g2.z+b2.z); o2[3]=f2bf((v2.w-mu)*rs*g2.w+b2.w);
  *reinterpret_cast<u16x4*>(op + lane*4)       = o0;
  *reinterpret_cast<u16x4*>(op + lane*4 + 256) = o1;
  *reinterpret_cast<u16x4*>(op + lane*4 + 512) = o2;
}

// ---------------- f32 -> bf16 convert (vectorized) ----------------
__global__ __launch_bounds__(256) void cvt_bf16(const float* __restrict__ in,
                                                u16* __restrict__ out, int n4)
{
  int i = blockIdx.x*256 + threadIdx.x;
  if (i < n4){
    float4 v = reinterpret_cast<const float4*>(in)[i];
    u16x4 o; o[0]=f2bf(v.x); o[1]=f2bf(v.y); o[2]=f2bf(v.z); o[3]=f2bf(v.w);
    *reinterpret_cast<u16x4*>(out + (size_t)i*4) = o;
  }
}

// ---------------- transpose + convert: in[R,Cc] f32 -> out[Cc,R] bf16 ----------------
__global__ __launch_bounds__(256) void transpose_cvt(const float* __restrict__ in,
    u16* __restrict__ out, int R, int Cc)
{
  __shared__ float tile[32][33];
  const int c0 = blockIdx.x*32, r0 = blockIdx.y*32;
  const int tx = threadIdx.x & 31, ty = threadIdx.x >> 5;
#pragma unroll
  for (int i=0;i<32;i+=8)
    tile[ty+i][tx] = in[(size_t)(r0+ty+i)*Cc + c0+tx];
  __syncthreads();
#pragma unroll
  for (int i=0;i<32;i+=8)
    out[(size_t)(c0+ty+i)*R + r0+tx] = f2bf(tile[tx][ty+i]);
}

// ---------------- mask sum per batch ----------------
__global__ __launch_bounds__(256) void msum_kernel(const float* __restrict__ mask,
                                                   float* __restrict__ msum)
{
  __shared__ float sm[4];
  const int b = blockIdx.x;
  float s = 0.f;
  for (int i=threadIdx.x;i<N_;i+=256) s += mask[(size_t)b*N_+i];
#pragma unroll
  for (int o=32;o>0;o>>=1) s += __shfl_down(s,o);
  if ((threadIdx.x&63)==0) sm[threadIdx.x>>6]=s;
  __syncthreads();
  if (threadIdx.x==0) msum[b] = sm[0]+sm[1]+sm[2]+sm[3];
}

// ---------------- masked pooling partials over n-chunks ----------------
__global__ __launch_bounds__(256) void pool_partial(const u16* __restrict__ q,
    const float* __restrict__ mask, float* __restrict__ pm, float* __restrict__ pa)
{
  const int c = blockIdx.x*256 + threadIdx.x;
  const int b = blockIdx.y, z = blockIdx.z;
  const int n0 = z*(N_/NSPLIT);
  const u16* qp = q + ((size_t)b*N_ + n0)*C_ + c;
  const float* mp = mask + (size_t)b*N_ + n0;
  float am=0.f, aa=0.f;
  for (int n=0;n<N_/NSPLIT;n++){
    float v = bf2f(qp[(size_t)n*C_]);
    float m = mp[n];
    am += v*m; aa += v;
  }
  const size_t o = ((size_t)z*B_ + b)*C_ + c;
  pm[o]=am; pa[o]=aa;
}

__global__ __launch_bounds__(256) void pool_final(const float* __restrict__ pm,
    const float* __restrict__ pa, const float* __restrict__ msum,
    float* __restrict__ fg, float* __restrict__ bg)
{
  const int c = blockIdx.x*256 + threadIdx.x;
  const int b = blockIdx.y;
  float s_m=0.f, s_a=0.f;
  for (int z=0;z<NSPLIT;z++){ size_t o=((size_t)z*B_+b)*C_+c; s_m+=pm[o]; s_a+=pa[o]; }
  const float ms = msum[b];
  fg[b*C_+c] = s_m/(ms + 5e-4f);
  bg[b*C_+c] = (s_a - s_m)/((float)N_ - ms + 5e-4f);
}

__global__ __launch_bounds__(256) void norm_kernel(const float* __restrict__ fg,
    const float* __restrict__ bg, float* __restrict__ fgn, float* __restrict__ bgn)
{
  __shared__ float sm[8];
  const int b = blockIdx.x;
  float f=0.f, g=0.f;
  for (int i=threadIdx.x;i<C_;i+=256){
    float a=fg[b*C_+i]; f+=a*a;
    float c=bg[b*C_+i]; g+=c*c;
  }
#pragma unroll
  for (int o=32;o>0;o>>=1){ f+=__shfl_down(f,o); g+=__shfl_down(g,o); }
  if ((threadIdx.x&63)==0){ sm[threadIdx.x>>6]=f; sm[4+(threadIdx.x>>6)]=g; }
  __syncthreads();
  if (threadIdx.x==0){
    fgn[b]=sqrtf(sm[0]+sm[1]+sm[2]+sm[3]);
    bgn[b]=sqrtf(sm[4]+sm[5]+sm[6]+sm[7]);
  }
}

// ---------------- cosine scores per token ----------------
__global__ __launch_bounds__(256) void score_kernel(const u16* __restrict__ k,
    const float* __restrict__ fg, const float* __restrict__ bg,
    const float* __restrict__ fgn, const float* __restrict__ bgn,
    float* __restrict__ fg_s, float* __restrict__ bg_s)
{
  __shared__ float sm[12];
  const int t = blockIdx.x;
  const int b = t >> 12;
  const u16* kp = k + (size_t)t*C_;
  float df=0.f, db=0.f, kk=0.f;
  for (int i=threadIdx.x;i<C_;i+=256){
    float kv = bf2f(kp[i]);
    df += kv*fg[b*C_+i]; db += kv*bg[b*C_+i]; kk += kv*kv;
  }
#pragma unroll
  for (int o=32;o>0;o>>=1){ df+=__shfl_down(df,o); db+=__shfl_down(db,o); kk+=__shfl_down(kk,o); }
  const int wid = threadIdx.x>>6;
  if ((threadIdx.x&63)==0){ sm[wid]=df; sm[4+wid]=db; sm[8+wid]=kk; }
  __syncthreads();
  if (threadIdx.x==0){
    df=sm[0]+sm[1]+sm[2]+sm[3]; db=sm[4]+sm[5]+sm[6]+sm[7]; kk=sm[8]+sm[9]+sm[10]+sm[11];
    const float kn = sqrtf(kk);
    fg_s[t] = df/(kn*fgn[b]+1e-7f);
    bg_s[t] = db/(kn*bgn[b]+1e-7f);
  }
}

__global__ __launch_bounds__(256) void minmax_kernel(const float* __restrict__ fg_s,
    const float* __restrict__ bg_s, float* __restrict__ mm)
{
  __shared__ float sm[16];
  const int b = blockIdx.x;
  float mnf=1e30f, mxf=-1e30f, mnb=1e30f, mxb=-1e30f;
  for (int i=threadIdx.x;i<N_;i+=256){
    float a = fg_s[(size_t)b*N_+i]; mnf=fminf(mnf,a); mxf=fmaxf(mxf,a);
    float c = bg_s[(size_t)b*N_+i]; mnb=fminf(mnb,c); mxb=fmaxf(mxb,c);
  }
#pragma unroll
  for (int o=32;o>0;o>>=1){
    mnf=fminf(mnf,__shfl_down(mnf,o)); mxf=fmaxf(mxf,__shfl_down(mxf,o));
    mnb=fminf(mnb,__shfl_down(mnb,o)); mxb=fmaxf(mxb,__shfl_down(mxb,o));
  }
  const int wid = threadIdx.x>>6;
  if ((threadIdx.x&63)==0){ sm[wid]=mnf; sm[4+wid]=mxf; sm[8+wid]=mnb; sm[12+wid]=mxb; }
  __syncthreads();
  if (threadIdx.x==0){
    mm[b*4+0]=fminf(fminf(sm[0],sm[1]),fminf(sm[2],sm[3]));
    mm[b*4+1]=fmaxf(fmaxf(sm[4],sm[5]),fmaxf(sm[6],sm[7]));
    mm[b*4+2]=fminf(fminf(sm[8],sm[9]),fminf(sm[10],sm[11]));
    mm[b*4+3]=fmaxf(fmaxf(sm[12],sm[13]),fmaxf(sm[14],sm[15]));
  }
}

// scores -> pseudo_mask out, exp weights, per-block exp partial sums
__global__ __launch_bounds__(256) void scorefin_kernel(const float* __restrict__ fg_s,
    const float* __restrict__ bg_s, const float* __restrict__ mm,
    float* __restrict__ pseudo, float* __restrict__ escr, float* __restrict__ epart)
{
  __shared__ float sm[4];
  const int b = blockIdx.y, z = blockIdx.x;
  const int t = z*256 + threadIdx.x;
  const size_t o = (size_t)b*N_ + t;
  const float mnf=mm[b*4+0], mxf=mm[b*4+1], mnb=mm[b*4+2], mxb=mm[b*4+3];
  const float s = (fg_s[o]-mnf)/(mxf-mnf+1e-7f) - (bg_s[o]-mnb)/(mxb-mnb+1e-7f);
  pseudo[o] = s;
  const float e = expf(s < 0.f ? s - 100.f : s);
  escr[o] = e;
  float ps = e;
#pragma unroll
  for (int off=32;off>0;off>>=1) ps += __shfl_down(ps,off);
  if ((threadIdx.x&63)==0) sm[threadIdx.x>>6]=ps;
  __syncthreads();
  if (threadIdx.x==0) epart[b*16+z] = sm[0]+sm[1]+sm[2]+sm[3];
}

__global__ void denom_kernel(const float* __restrict__ epart, float* __restrict__ denom){
  const int b = threadIdx.x;
  if (b < B_){ float s=0.f; for (int z=0;z<16;z++) s+=epart[b*16+z]; denom[b]=s; }
}

__global__ __launch_bounds__(256) void vsum_partial(const u16* __restrict__ v,
    const float* __restrict__ e, float* __restrict__ pv)
{
  const int c = blockIdx.x*256 + threadIdx.x;
  const int b = blockIdx.y, z = blockIdx.z;
  const int n0 = z*(N_/NSPLIT);
  const u16* vp = v + ((size_t)b*N_ + n0)*C_ + c;
  const float* ep = e + (size_t)b*N_ + n0;
  float acc=0.f;
  for (int n=0;n<N_/NSPLIT;n++) acc += bf2f(vp[(size_t)n*C_])*ep[n];
  pv[((size_t)z*B_+b)*C_+c] = acc;
}

__global__ __launch_bounds__(256) void vsum_final(const float* __restrict__ pv,
    const float* __restrict__ denom, float* __restrict__ qp)
{
  const int c = blockIdx.x*256 + threadIdx.x;
  const int b = blockIdx.y;
  float s=0.f;
  for (int z=0;z<NSPLIT;z++) s += pv[((size_t)z*B_+b)*C_+c];
  qp[b*C_+c] = s/denom[b];
}

__global__ __launch_bounds__(256) void pro_kernel(const float* __restrict__ qp,
    const float* __restrict__ fg, const float* __restrict__ fgn, float* __restrict__ pro)
{
  __shared__ float sm[8];
  __shared__ float simsh;
  const int b = blockIdx.x;
  float d=0.f, qq=0.f;
  for (int i=threadIdx.x;i<C_;i+=256){ float a=qp[b*C_+i]; d+=a*fg[b*C_+i]; qq+=a*a; }
#pragma unroll
  for (int o=32;o>0;o>>=1){ d+=__shfl_down(d,o); qq+=__shfl_down(qq,o); }
  if ((threadIdx.x&63)==0){ sm[threadIdx.x>>6]=d; sm[4+(threadIdx.x>>6)]=qq; }
  __syncthreads();
  if (threadIdx.x==0){
    d=sm[0]+sm[1]+sm[2]+sm[3]; qq=sm[4]+sm[5]+sm[6]+sm[7];
    simsh = (d/(sqrtf(qq)*fgn[b]+1e-7f)+1.f)*0.5f;
  }
  __syncthreads();
  const float sim = simsh;
  for (int i=threadIdx.x;i<C_;i+=256)
    pro[b*C_+i] = sim*fg[b*C_+i] + (1.f-sim)*qp[b*C_+i];
}

// rowv[b][j] = sum_c pro[b][c] * Wp[(C_+c)*C_ + j]   (bottom half of Wpx/Wpy, f32)
__global__ __launch_bounds__(256) void rowvec_kernel(const float* __restrict__ pro,
    const float* __restrict__ Wp, float* __restrict__ row)
{
  const int j = blockIdx.x*256 + threadIdx.x;
  const int b = blockIdx.y;
  const float* w = Wp + (size_t)C_*C_ + j;
  const float* p = pro + b*C_;
  float acc=0.f;
#pragma unroll 4
  for (int c=0;c<C_;c++) acc += p[c]*w[(size_t)c*C_];
  row[b*C_+j] = acc;
}

// ---------------- launcher ----------------
extern "C" void kernel_launch(void* const* d_in, const int* in_sizes, int n_in,
                              void* d_out, int out_size, void* d_ws, size_t ws_size,
                              hipStream_t stream)
{
  const float* x     = (const float*)d_in[0];
  const float* y     = (const float*)d_in[1];
  const float* mask  = (const float*)d_in[2];
  const float* ln1_g = (const float*)d_in[5];
  const float* ln1_b = (const float*)d_in[6];
  const float* Wq    = (const float*)d_in[7];
  const float* Wk    = (const float*)d_in[8];
  const float* Wv    = (const float*)d_in[9];
  const float* Wpx   = (const float*)d_in[10];
  const float* Wpy   = (const float*)d_in[11];
  const float* ln2_g = (const float*)d_in[12];
  const float* ln2_b = (const float*)d_in[13];
  const float* fx1_w = (const float*)d_in[14];
  const float* fx1_b = (const float*)d_in[15];
  const float* fx2_w = (const float*)d_in[16];
  const float* fx2_b = (const float*)d_in[17];
  const float* fy1_w = (const float*)d_in[18];
  const float* fy1_b = (const float*)d_in[19];
  const float* fy2_w = (const float*)d_in[20];
  const float* fy2_b = (const float*)d_in[21];

  float* out    = (float*)d_out;
  float* out_xo = out;
  float* out_yo = out + (size_t)M_*C_;
  float* out_ps = out + 2*(size_t)M_*C_;

  char* ws = (char*)d_ws;
  const size_t ACT = (size_t)M_*C_;        // 25165824 elems
  u16* R0  = (u16*)ws;
  u16* xnb = R0;                           // xn bf16 (later: x bf16)
  u16* ynb = R0 + ACT;                     // yn bf16 (later: y bf16)
  u16* kb  = R0 + 2*ACT;                   // k bf16
  u16* vb  = R0 + 3*ACT;                   // v bf16
  u16* hid = R0;                           // MLP hidden bf16 [M,H] aliases all of R0
  u16* qb  = (u16*)(ws + 4*ACT*2);         // q bf16 (later: ln2 out bf16)
  u16* wp  = (u16*)(ws + 5*ACT*2);         // bf16 weights
  u16* WqT  = wp;
  u16* WkT  = wp + 1*589824;
  u16* WvT  = wp + 2*589824;
  u16* WpxT = wp + 3*589824;
  u16* WpyT = wp + 4*589824;
  u16* fx1T = wp + 5*589824;
  u16* fx2T = fx1T + 2359296;
  u16* fy1T = fx2T + 2359296;
  u16* fy2T = fy1T + 2359296;
  float* st   = (float*)(ws + 5*ACT*2 + 24772608);
  float* msum = st;             // 8
  float* fgn  = st + 8;         // 8
  float* bgn  = st + 16;        // 8
  float* denom= st + 24;        // 8
  float* mm   = st + 32;        // 32
  float* fg   = st + 64;        // 6144
  float* bg   = st + 6208;      // 6144
  float* qp   = st + 12352;     // 6144
  float* pro  = st + 18496;     // 6144
  float* rowx = st + 24640;     // 6144
  float* rowy = st + 30784;     // 6144
  float* epart= st + 36928;     // 128
  float* fg_s = st + 37056;     // 32768
  float* bg_s = st + 69824;     // 32768
  float* escr = st + 102592;    // 32768
  float* pm   = st + 135360;    // 98304
  float* pa   = st + 233664;    // 98304
  float* pv   = st + 331968;    // 98304

  dim3 tb(256);

  // --- weights -> bf16, transposed to [N,K] ---
  transpose_cvt<<<dim3(24,24),tb,0,stream>>>(Wq,  WqT,  C_, C_);
  transpose_cvt<<<dim3(24,24),tb,0,stream>>>(Wk,  WkT,  C_, C_);
  transpose_cvt<<<dim3(24,24),tb,0,stream>>>(Wv,  WvT,  C_, C_);
  transpose_cvt<<<dim3(24,24),tb,0,stream>>>(Wpx, WpxT, C_, C_);
  transpose_cvt<<<dim3(24,24),tb,0,stream>>>(Wpy, WpyT, C_, C_);
  transpose_cvt<<<dim3(96,24),tb,0,stream>>>(fx1_w, fx1T, C_, H_);
  transpose_cvt<<<dim3(24,96),tb,0,stream>>>(fx2_w, fx2T, H_, C_);
  transpose_cvt<<<dim3(96,24),tb,0,stream>>>(fy1_w, fy1T, C_, H_);
  transpose_cvt<<<dim3(24,96),tb,0,stream>>>(fy2_w, fy2T, H_, C_);

  // --- LN1 ---
  ln_fwd<<<M_/4,tb,0,stream>>>(x, ln1_g, ln1_b, xnb);
  ln_fwd<<<M_/4,tb,0,stream>>>(y, ln1_g, ln1_b, ynb);

  // --- q,k,v GEMMs ---
  gemm_bf16<0><<<dim3(256*6),tb,0,stream>>>(ynb, WqT, C_, C_, 6, qb, nullptr,nullptr,nullptr);
  gemm_bf16<0><<<dim3(256*6),tb,0,stream>>>(xnb, WkT, C_, C_, 6, kb, nullptr,nullptr,nullptr);
  gemm_bf16<0><<<dim3(256*6),tb,0,stream>>>(xnb, WvT, C_, C_, 6, vb, nullptr,nullptr,nullptr);

  // --- pooled prototypes + scores ---
  msum_kernel<<<B_,tb,0,stream>>>(mask, msum);
  pool_partial<<<dim3(3,B_,NSPLIT),tb,0,stream>>>(qb, mask, pm, pa);
  pool_final<<<dim3(3,B_),tb,0,stream>>>(pm, pa, msum, fg, bg);
  norm_kernel<<<B_,tb,0,stream>>>(fg, bg, fgn, bgn);
  score_kernel<<<M_,tb,0,stream>>>(kb, fg, bg, fgn, bgn, fg_s, bg_s);
  minmax_kernel<<<B_,tb,0,stream>>>(fg_s, bg_s, mm);
  scorefin_kernel<<<dim3(16,B_),tb,0,stream>>>(fg_s, bg_s, mm, out_ps, escr, epart);
  denom_kernel<<<1,64,0,stream>>>(epart, denom);
  vsum_partial<<<dim3(3,B_,NSPLIT),tb,0,stream>>>(vb, escr, pv);
  vsum_final<<<dim3(3,B_),tb,0,stream>>>(pv, denom, qp);
  pro_kernel<<<B_,tb,0,stream>>>(qp, fg, fgn, pro);
  rowvec_kernel<<<dim3(3,B_),tb,0,stream>>>(pro, Wpx, rowx);
  rowvec_kernel<<<dim3(3,B_),tb,0,stream>>>(pro, Wpy, rowy);

  // --- x,y -> bf16 (reuse xn/yn slots; xn/yn dead after qkv GEMMs) ---
  cvt_bf16<<<(ACT/4+255)/256,tb,0,stream>>>(x, xnb, (int)(ACT/4));
  cvt_bf16<<<(ACT/4+255)/256,tb,0,stream>>>(y, ynb, (int)(ACT/4));

  // --- projection GEMMs: out = resid + act@WpA + pro@WpB ---
  gemm_bf16<1><<<dim3(256*6),tb,0,stream>>>(xnb, WpxT, C_, C_, 6, out_xo, x, rowx, nullptr);
  gemm_bf16<1><<<dim3(256*6),tb,0,stream>>>(ynb, WpyT, C_, C_, 6, out_yo, y, rowy, nullptr);

  // --- x MLP ---
  ln_fwd<<<M_/4,tb,0,stream>>>(out_xo, ln2_g, ln2_b, qb);
  gemm_bf16<2><<<dim3(256*24),tb,0,stream>>>(qb, fx1T, C_, H_, 24, hid, nullptr,nullptr, fx1_b);
  gemm_bf16<3><<<dim3(256*6),tb,0,stream>>>(hid, fx2T, H_, C_, 6, out_xo, nullptr,nullptr, fx2_b);

  // --- y MLP ---
  ln_fwd<<<M_/4,tb,0,stream>>>(out_yo, ln2_g, ln2_b, qb);
  gemm_bf16<2><<<dim3(256*24),tb,0,stream>>>(qb, fy1T, C_, H_, 24, hid, nullptr,nullptr, fy1_b);
  gemm_bf16<3><<<dim3(256*6),tb,0,stream>>>(hid, fy2T, H_, C_, 6, out_yo, nullptr,nullptr, fy2_b);
}